// Round 11
// baseline (32.759 us; speedup 1.0000x reference)
//
#include <hip/hip_runtime.h>

#define BB 16
#define SS 16
#define LL 128
#define DD 768
#define AA 8
#define TT 8
#define PAD_ID 1
#define NARG 24          // 3 arg types * 8 args
#define NROW 25
#define NT1 384          // prep kernel threads
#define NT2 768          // stream kernel threads (12 waves)
#define NQ 96            // float4 col-quads per block (384 cols)
#define NSEG 8           // in-block L split
#define SEGL 16          // LL / NSEG
#define COLS 384         // cols per block

// ---------------- Kernel 1: per-(b,s) weight precompute ----------------
__global__ __launch_bounds__(NT1) void srl_prep(
    const int* __restrict__ sid_g,
    const int* __restrict__ mask_g,
    const int* __restrict__ pred_g,
    const int* __restrict__ a0_g,
    const int* __restrict__ a1_g,
    float* __restrict__ Wfull,      // [B*S][25][128]
    int* __restrict__ hdr)          // [B*S][32]: 0=nact, 1..24=actlist(-1 pad)
{
    __shared__ int   sid[LL];
    __shared__ float maskf[LL];
    __shared__ float coeff[NARG][TT];
    __shared__ float validf[NARG][TT];
    __shared__ int   toks[NARG][TT];
    __shared__ float inv_msum;
    __shared__ int   amask_sh;
    __shared__ int   nact_sh;
    __shared__ int   actlist[NARG];

    const int bs  = blockIdx.x;
    const int tid = threadIdx.x;

    if (tid < LL) {
        sid[tid]   = sid_g[bs * LL + tid];
        maskf[tid] = (float)mask_g[bs * LL + tid];
    }
    if (tid == 0) amask_sh = 0;
    __syncthreads();

    if (tid < NARG * TT) {
        const int j = tid >> 3;
        const int t = tid & 7;
        const int k = j >> 3;
        const int a = j & 7;
        const int* src = (k == 0) ? pred_g : (k == 1) ? a0_g : a1_g;
        const int tok = src[bs * AA * TT + a * TT + t];
        int cnt = 0;
        for (int l = 0; l < LL; ++l) cnt += (sid[l] == tok) ? 1 : 0;
        const float v = (tok != PAD_ID) ? 1.0f : 0.0f;
        toks[j][t]   = tok;
        validf[j][t] = v;
        coeff[j][t]  = v / (float)(cnt > 1 ? cnt : 1);
        if (v != 0.0f && cnt > 0) atomicOr(&amask_sh, 1 << j);
    } else if (tid >= 320 && tid < 384) {
        const int lane = tid - 320;
        float s = maskf[lane] + maskf[lane + 64];
        for (int off = 32; off; off >>= 1) s += __shfl_xor(s, off, 64);
        if (lane == 0) inv_msum = 1.0f / fmaxf(s, 1.0f);
    }
    __syncthreads();

    if (tid < NARG) {
        float nv = 0.0f;
        #pragma unroll
        for (int t = 0; t < TT; ++t) nv += validf[tid][t];
        const float inv = 1.0f / fmaxf(nv, 1.0f);
        #pragma unroll
        for (int t = 0; t < TT; ++t) coeff[tid][t] *= inv;
    } else if (tid == NARG) {
        int n = 0;
        const int m = amask_sh;
        for (int j = 0; j < NARG; ++j)
            if ((m >> j) & 1) actlist[n++] = j;
        nact_sh = n;
        for (int s = n; s < NARG; ++s) actlist[s] = -1;
    }
    __syncthreads();

    // Full 25x128 weight matrix to global
    for (int idx = tid; idx < NROW * LL; idx += NT1) {
        const int r = idx >> 7;         // 0..24
        const int l = idx & (LL - 1);
        float w;
        if (r == 0) {
            w = maskf[l] * inv_msum;
        } else {
            const int j  = r - 1;
            const int sl = sid[l];
            w = 0.0f;
            #pragma unroll
            for (int t = 0; t < TT; ++t)
                w += (sl == toks[j][t]) ? coeff[j][t] : 0.0f;
        }
        Wfull[((size_t)bs * NROW + r) * LL + l] = w;
    }
    if (tid == NT1 - 1) {
        hdr[bs * 32] = nact_sh;
        for (int s = 0; s < NARG; ++s) hdr[bs * 32 + 1 + s] = actlist[s];
    }
}

// ---------------- Kernel 2: pure streaming reduction ----------------
__global__ __launch_bounds__(NT2, 8) void srl_stream(
    const float* __restrict__ emb_g,
    const float* __restrict__ Wfull,
    const int* __restrict__ hdr,
    float* __restrict__ out)
{
    __shared__ float  Wt4[LL][4];       // slot-packed weights (slot0 = mean)
    __shared__ int    slotmap[NARG];
    __shared__ int    actlist_sh[NARG];
    __shared__ int    nact_sh;
    __shared__ float4 P4[NSEG][NQ][4];  // 48 KB
    __shared__ float  Wx[LL];

    const int bs  = blockIdx.x;
    const int cc  = blockIdx.y;
    const int tid = threadIdx.x;
    const int q   = tid % NQ;
    const int seg = tid / NQ;

    float* out0 = out;
    float* outA = out + (size_t)BB * SS * DD;
    const int colbase = cc * COLS + 4 * q;

    // Early prefetch: first 2 rows in flight before setup
    const float* ep = emb_g + (size_t)bs * (LL * DD)
                    + (size_t)(seg * SEGL) * DD + colbase;
    float4 cur0 = *reinterpret_cast<const float4*>(&ep[0]);
    float4 cur1 = *reinterpret_cast<const float4*>(&ep[DD]);

    // Minimal setup: 4 weight rows + header
    if (tid < LL * 4) {
        const int l = tid >> 2;
        const int s = tid & 3;
        float w;
        if (s == 0) {
            w = Wfull[((size_t)bs * NROW) * LL + l];
        } else {
            const int j = hdr[bs * 32 + s];     // actlist[s-1], -1 if none
            w = (j >= 0) ? Wfull[((size_t)bs * NROW + j + 1) * LL + l] : 0.0f;
        }
        Wt4[l][s] = w;
    } else if (tid == LL * 4) {
        const int n = hdr[bs * 32];
        nact_sh = n;
        for (int j = 0; j < NARG; ++j) slotmap[j] = -1;
        for (int s = 0; s < NARG; ++s) actlist_sh[s] = hdr[bs * 32 + 1 + s];
        for (int s = 0; s < 3 && s < n; ++s) slotmap[actlist_sh[s]] = s + 1;
    }
    __syncthreads();

    // Stream: 16-row segment, 4 cols, 2-row pipeline
    float4 acc0 = make_float4(0.f, 0.f, 0.f, 0.f);
    float4 acc1 = acc0, acc2 = acc0, acc3 = acc0;
    #pragma unroll
    for (int l0 = 0; l0 < SEGL; l0 += 2) {
        float4 nxt0, nxt1;
        if (l0 + 2 < SEGL) {
            nxt0 = *reinterpret_cast<const float4*>(&ep[(size_t)(l0 + 2) * DD]);
            nxt1 = *reinterpret_cast<const float4*>(&ep[(size_t)(l0 + 3) * DD]);
        }
        {
            const float4 w = *reinterpret_cast<const float4*>(&Wt4[seg * SEGL + l0][0]);
            const float4 e = cur0;
            acc0.x += w.x * e.x; acc0.y += w.x * e.y; acc0.z += w.x * e.z; acc0.w += w.x * e.w;
            acc1.x += w.y * e.x; acc1.y += w.y * e.y; acc1.z += w.y * e.z; acc1.w += w.y * e.w;
            acc2.x += w.z * e.x; acc2.y += w.z * e.y; acc2.z += w.z * e.z; acc2.w += w.z * e.w;
            acc3.x += w.w * e.x; acc3.y += w.w * e.y; acc3.z += w.w * e.z; acc3.w += w.w * e.w;
        }
        {
            const float4 w = *reinterpret_cast<const float4*>(&Wt4[seg * SEGL + l0 + 1][0]);
            const float4 e = cur1;
            acc0.x += w.x * e.x; acc0.y += w.x * e.y; acc0.z += w.x * e.z; acc0.w += w.x * e.w;
            acc1.x += w.y * e.x; acc1.y += w.y * e.y; acc1.z += w.y * e.z; acc1.w += w.y * e.w;
            acc2.x += w.z * e.x; acc2.y += w.z * e.y; acc2.z += w.z * e.z; acc2.w += w.z * e.w;
            acc3.x += w.w * e.x; acc3.y += w.w * e.y; acc3.z += w.w * e.z; acc3.w += w.w * e.w;
        }
        cur0 = nxt0;
        cur1 = nxt1;
    }
    P4[seg][q][0] = acc0;
    P4[seg][q][1] = acc1;
    P4[seg][q][2] = acc2;
    P4[seg][q][3] = acc3;
    __syncthreads();

    // Combine across segments; store all 25 rows (zeros for inactive)
    {
        const int g = seg;
        #pragma unroll
        for (int i = 0; i < 4; ++i) {
            const int r = g + 8 * i;
            if (r >= NROW) break;
            float4 val = make_float4(0.f, 0.f, 0.f, 0.f);
            int s = -1;
            if (r == 0) s = 0;
            else if (slotmap[r - 1] >= 0) s = slotmap[r - 1];
            if (s >= 0) {
                #pragma unroll
                for (int g2 = 0; g2 < NSEG; ++g2) {
                    const float4 p = P4[g2][q][s];
                    val.x += p.x; val.y += p.y; val.z += p.z; val.w += p.w;
                }
            }
            if (r == 0) {
                *reinterpret_cast<float4*>(&out0[(size_t)bs * DD + colbase]) = val;
            } else {
                const int j = r - 1;
                *reinterpret_cast<float4*>(
                    &outA[(size_t)(j >> 3) * (BB * SS * AA * DD) +
                          ((size_t)bs * AA + (j & 7)) * DD + colbase]) = val;
            }
        }
    }

    // Rare: >3 active rows -> extra sweeps, weights straight from global
    for (int e = 3; e < nact_sh; ++e) {
        const int je = actlist_sh[e];
        __syncthreads();
        if (tid < LL)
            Wx[tid] = Wfull[((size_t)bs * NROW + je + 1) * LL + tid];
        __syncthreads();
        float4 acc = make_float4(0.f, 0.f, 0.f, 0.f);
        for (int l = 0; l < SEGL; ++l) {
            const float w = Wx[seg * SEGL + l];
            const float4 ev = *reinterpret_cast<const float4*>(&ep[(size_t)l * DD]);
            acc.x += w * ev.x; acc.y += w * ev.y; acc.z += w * ev.z; acc.w += w * ev.w;
        }
        P4[seg][q][0] = acc;
        __syncthreads();
        if (seg == 0) {
            float4 s = make_float4(0.f, 0.f, 0.f, 0.f);
            #pragma unroll
            for (int g2 = 0; g2 < NSEG; ++g2) {
                const float4 p = P4[g2][q][0];
                s.x += p.x; s.y += p.y; s.z += p.z; s.w += p.w;
            }
            *reinterpret_cast<float4*>(
                &outA[(size_t)(je >> 3) * (BB * SS * AA * DD) +
                      ((size_t)bs * AA + (je & 7)) * DD + colbase]) = s;
        }
    }
}

extern "C" void kernel_launch(void* const* d_in, const int* in_sizes, int n_in,
                              void* d_out, int out_size, void* d_ws, size_t ws_size,
                              hipStream_t stream) {
    const int*   sid  = (const int*)d_in[0];
    const int*   mask = (const int*)d_in[1];
    const float* emb  = (const float*)d_in[2];
    const int*   pred = (const int*)d_in[3];
    const int*   a0   = (const int*)d_in[4];
    const int*   a1   = (const int*)d_in[5];
    float* outp = (float*)d_out;

    float* Wfull = (float*)d_ws;                                  // 3.28 MB
    int*   hdr   = (int*)((char*)d_ws + (size_t)BB * SS * NROW * LL * sizeof(float));

    srl_prep<<<dim3(BB * SS), dim3(NT1), 0, stream>>>(
        sid, mask, pred, a0, a1, Wfull, hdr);
    srl_stream<<<dim3(BB * SS, DD / COLS), dim3(NT2), 0, stream>>>(
        emb, Wfull, hdr, outp);
}

// Round 13
// 28.676 us; speedup vs baseline: 1.1424x; 1.1424x over previous
//
#include <hip/hip_runtime.h>

#define BB 16
#define SS 16
#define LL 128
#define DD 768
#define AA 8
#define TT 8
#define PAD_ID 1
#define NARG 24          // 3 arg types * 8 args
#define NT 768           // 12 waves
#define NQ 96            // float4 col-quads per block (384 cols)
#define NSEG 8           // in-block L split
#define SEGL 16          // LL / NSEG
#define CH 8             // rows per pipeline stage (SEGL = 2*CH)
#define COLS 384         // cols per block

typedef float f4 __attribute__((ext_vector_type(4)));  // native vec for nt builtins

__global__ __launch_bounds__(NT) void srl_kernel(
    const int* __restrict__ sid_g,
    const int* __restrict__ mask_g,
    const float* __restrict__ emb_g,
    const int* __restrict__ pred_g,
    const int* __restrict__ a0_g,
    const int* __restrict__ a1_g,
    float* __restrict__ out)
{
    __shared__ int    sid[LL];
    __shared__ float  maskf[LL];
    __shared__ float  Wt4[LL][4];       // slot-packed weights (slot0 = mean row)
    __shared__ float  coeff[NARG][TT];
    __shared__ float  validf[NARG][TT];
    __shared__ int    toks[NARG][TT];
    __shared__ float  inv_msum;
    __shared__ int    amask_sh;
    __shared__ int    nact_sh;
    __shared__ int    actlist[NARG];
    __shared__ int    slotmap[NARG];    // row j -> slot 1..3, or -1
    __shared__ f4     P4[NSEG][NQ][4];  // cross-segment partials (48 KB)
    __shared__ float  Wx[LL];           // weights for rare extra rows

    const int bs  = blockIdx.x;
    const int cc  = blockIdx.y;
    const int tid = threadIdx.x;
    const int q   = tid % NQ;           // col-quad within block
    const int seg = tid / NQ;           // 0..7

    float* out0 = out;                               // [B*S, D]
    float* outA = out + (size_t)BB * SS * DD;        // 3 x [B*S, A, D]
    const int colbase = cc * COLS + 4 * q;

    // ---- Early prefetch: first chunk's E loads issued BEFORE setup so their
    //      HBM latency hides under phases A-C. Nontemporal: one-touch stream.
    const float* ep = emb_g + (size_t)bs * (LL * DD)
                    + (size_t)(seg * SEGL) * DD + colbase;
    f4 cur[CH], nxt[CH];
    #pragma unroll
    for (int j = 0; j < CH; ++j)
        cur[j] = __builtin_nontemporal_load(
            reinterpret_cast<const f4*>(&ep[(size_t)j * DD]));

    // ---- Phase A: stage sentence ids + mask ----
    if (tid < LL) {
        sid[tid]   = sid_g[bs * LL + tid];
        maskf[tid] = (float)mask_g[bs * LL + tid];
    }
    if (tid == 0) amask_sh = 0;
    __syncthreads();

    // ---- Phase B1: per-token match count + valid (threads 0..191),
    //      mask-sum on threads 320..383 ----
    if (tid < NARG * TT) {
        const int j = tid >> 3;
        const int t = tid & 7;
        const int k = j >> 3;
        const int a = j & 7;
        const int* src = (k == 0) ? pred_g : (k == 1) ? a0_g : a1_g;
        const int tok = src[bs * AA * TT + a * TT + t];
        int cnt = 0;
        for (int l = 0; l < LL; ++l) cnt += (sid[l] == tok) ? 1 : 0;
        const float v = (tok != PAD_ID) ? 1.0f : 0.0f;
        toks[j][t]   = tok;
        validf[j][t] = v;
        coeff[j][t]  = v / (float)(cnt > 1 ? cnt : 1);
        if (v != 0.0f && cnt > 0) atomicOr(&amask_sh, 1 << j);
    } else if (tid >= 320 && tid < 384) {
        const int lane = tid - 320;
        float s = maskf[lane] + maskf[lane + 64];
        for (int off = 32; off; off >>= 1) s += __shfl_xor(s, off, 64);
        if (lane == 0) inv_msum = 1.0f / fmaxf(s, 1.0f);
    }
    __syncthreads();

    // ---- Phase B2: fold 1/n_valid; build active-row list + slot map ----
    if (tid < NARG) {
        float nv = 0.0f;
        #pragma unroll
        for (int t = 0; t < TT; ++t) nv += validf[tid][t];
        const float inv = 1.0f / fmaxf(nv, 1.0f);
        #pragma unroll
        for (int t = 0; t < TT; ++t) coeff[tid][t] *= inv;
    } else if (tid == NARG) {
        int n = 0;
        const int m = amask_sh;
        for (int j = 0; j < NARG; ++j) {
            slotmap[j] = -1;
            if ((m >> j) & 1) actlist[n++] = j;
        }
        nact_sh = n;
        for (int s = n; s < NARG; ++s) actlist[s] = -1;
        for (int s = 0; s < n && s < 3; ++s) slotmap[actlist[s]] = s + 1;
    }
    __syncthreads();

    // ---- Phase C: slot-packed weights (threads 0..511) ----
    if (tid < LL * 4) {
        const int l = tid >> 2;
        const int s = tid & 3;
        float w = 0.0f;
        if (s == 0) {
            w = maskf[l] * inv_msum;
        } else {
            const int j = actlist[s - 1];
            if (j >= 0) {
                const int sl = sid[l];
                #pragma unroll
                for (int t = 0; t < TT; ++t)
                    w += (sl == toks[j][t]) ? coeff[j][t] : 0.0f;
            }
        }
        Wt4[l][s] = w;
    }
    __syncthreads();

    // ---- Phase D: each thread sweeps its 16-row segment, 4 cols ----
    f4 acc0 = (f4)(0.0f);
    f4 acc1 = acc0, acc2 = acc0, acc3 = acc0;
    {
        #pragma unroll
        for (int l0 = 0; l0 < SEGL; l0 += CH) {
            if (l0 + CH < SEGL) {
                #pragma unroll
                for (int j = 0; j < CH; ++j)
                    nxt[j] = __builtin_nontemporal_load(
                        reinterpret_cast<const f4*>(&ep[(size_t)(l0 + CH + j) * DD]));
            }
            #pragma unroll
            for (int j = 0; j < CH; ++j) {
                const f4 w = *reinterpret_cast<const f4*>(&Wt4[seg * SEGL + l0 + j][0]);
                const f4 e = cur[j];
                acc0 += w.x * e;
                acc1 += w.y * e;
                acc2 += w.z * e;
                acc3 += w.w * e;
            }
            #pragma unroll
            for (int j = 0; j < CH; ++j) cur[j] = nxt[j];
        }
    }
    P4[seg][q][0] = acc0;
    P4[seg][q][1] = acc1;
    P4[seg][q][2] = acc2;
    P4[seg][q][3] = acc3;
    __syncthreads();

    // ---- Combine across segments; store all 25 rows (zeros for inactive) ----
    {
        const int g = seg;              // 0..7
        #pragma unroll
        for (int i = 0; i < 4; ++i) {
            const int r = g + 8 * i;    // rows 0..24 covered
            if (r >= 25) break;
            f4 val = (f4)(0.0f);
            int s = -1;
            if (r == 0) s = 0;
            else if (slotmap[r - 1] >= 0) s = slotmap[r - 1];
            if (s >= 0) {
                #pragma unroll
                for (int g2 = 0; g2 < NSEG; ++g2)
                    val += P4[g2][q][s];
            }
            if (r == 0) {
                __builtin_nontemporal_store(val,
                    reinterpret_cast<f4*>(&out0[(size_t)bs * DD + colbase]));
            } else {
                const int j = r - 1;
                __builtin_nontemporal_store(val,
                    reinterpret_cast<f4*>(
                        &outA[(size_t)(j >> 3) * (BB * SS * AA * DD) +
                              ((size_t)bs * AA + (j & 7)) * DD + colbase]));
            }
        }
    }

    // ---- Rare: more than 3 active rows -> extra block-uniform sweeps ----
    for (int e = 3; e < nact_sh; ++e) {
        const int je = actlist[e];
        __syncthreads();
        if (tid < LL) {
            const int sl = sid[tid];
            float w = 0.0f;
            #pragma unroll
            for (int t = 0; t < TT; ++t)
                w += (sl == toks[je][t]) ? coeff[je][t] : 0.0f;
            Wx[tid] = w;
        }
        __syncthreads();
        f4 acc = (f4)(0.0f);
        for (int l = 0; l < SEGL; ++l) {
            const float w = Wx[seg * SEGL + l];
            const f4 ev = *reinterpret_cast<const f4*>(&ep[(size_t)l * DD]);
            acc += w * ev;
        }
        P4[seg][q][0] = acc;
        __syncthreads();
        if (seg == 0) {
            f4 s = (f4)(0.0f);
            #pragma unroll
            for (int g2 = 0; g2 < NSEG; ++g2)
                s += P4[g2][q][0];
            *reinterpret_cast<f4*>(
                &outA[(size_t)(je >> 3) * (BB * SS * AA * DD) +
                      ((size_t)bs * AA + (je & 7)) * DD + colbase]) = s;
        }
    }
}

extern "C" void kernel_launch(void* const* d_in, const int* in_sizes, int n_in,
                              void* d_out, int out_size, void* d_ws, size_t ws_size,
                              hipStream_t stream) {
    const int*   sid  = (const int*)d_in[0];
    const int*   mask = (const int*)d_in[1];
    const float* emb  = (const float*)d_in[2];
    const int*   pred = (const int*)d_in[3];
    const int*   a0   = (const int*)d_in[4];
    const int*   a1   = (const int*)d_in[5];
    float* outp = (float*)d_out;

    srl_kernel<<<dim3(BB * SS, DD / COLS), dim3(NT), 0, stream>>>(
        sid, mask, emb, pred, a0, a1, outp);
}